// Round 2
// baseline (54.669 us; speedup 1.0000x reference)
//
#include <hip/hip_runtime.h>
#include <math.h>

// Problem constants (B=256, S=512, J=32, D=3)
constexpr int NGROUPS = 256 * 512 * 32;   // 4,194,304 (b,s,j) groups
constexpr int NQUAD   = NGROUPS / 4;      // 1,048,576 quads, 1 per thread
constexpr int BLOCK   = 256;
constexpr int GRID    = NQUAD / BLOCK;    // 4096 blocks, exact fit

#define LOG_2PI 1.8378770664093453f

typedef float f32x4 __attribute__((ext_vector_type(4)));

__device__ __forceinline__ float fast_rcp(float x) {
    return __builtin_amdgcn_rcpf(x);
}

__global__ __launch_bounds__(BLOCK) void nll_main(
    const float* __restrict__ yt,
    const float* __restrict__ yp,
    const float* __restrict__ Lm,
    float* __restrict__ partial)
{
    const f32x4* yt4 = reinterpret_cast<const f32x4*>(yt);
    const f32x4* yp4 = reinterpret_cast<const f32x4*>(yp);
    const f32x4* L4  = reinterpret_cast<const f32x4*>(Lm);

    const int q = blockIdx.x * BLOCK + threadIdx.x;   // one quad (4 groups)

    // y streams: non-temporal (no L3 pollution) -- they have zero reuse and
    // excluding them lets the 151 MB L tensor stay Infinity-Cache-resident
    // across graph replays.
    float d[12];
    #pragma unroll
    for (int i = 0; i < 3; ++i) {
        f32x4 a = __builtin_nontemporal_load(&yt4[q * 3 + i]);
        f32x4 b = __builtin_nontemporal_load(&yp4[q * 3 + i]);
        d[i * 4 + 0] = a.x - b.x;
        d[i * 4 + 1] = a.y - b.y;
        d[i * 4 + 2] = a.z - b.z;
        d[i * 4 + 3] = a.w - b.w;
    }
    // L: normal loads, want L3 residency.
    float l[36];
    #pragma unroll
    for (int i = 0; i < 9; ++i) {
        f32x4 v = L4[q * 9 + i];
        l[i * 4 + 0] = v.x;
        l[i * 4 + 1] = v.y;
        l[i * 4 + 2] = v.z;
        l[i * 4 + 3] = v.w;
    }

    float acc = 0.0f;
    #pragma unroll
    for (int g = 0; g < 4; ++g) {
        // row-major 3x3: [0]=L00 [3]=L10 [4]=L11 [6]=L20 [7]=L21 [8]=L22
        float L00 = l[g * 9 + 0];
        float L10 = l[g * 9 + 3];
        float L11 = l[g * 9 + 4];
        float L20 = l[g * 9 + 6];
        float L21 = l[g * 9 + 7];
        float L22 = l[g * 9 + 8];
        float d0 = d[g * 3 + 0];
        float d1 = d[g * 3 + 1];
        float d2 = d[g * 3 + 2];

        float r0 = fast_rcp(L00);
        float r1 = fast_rcp(L11);
        float r2 = fast_rcp(L22);
        float x0 = d0 * r0;
        float x1 = (d1 - L10 * x0) * r1;
        float x2 = (d2 - L20 * x0 - L21 * x1) * r2;
        float maha   = x0 * x0 + x1 * x1 + x2 * x2;
        float logdet = __logf(L00) + __logf(L11) + __logf(L22); // *2 folded below
        acc += 0.5f * maha + logdet;   // constant term added in final reduce
    }

    // wave (64-lane) shuffle reduce
    #pragma unroll
    for (int off = 32; off > 0; off >>= 1) acc += __shfl_down(acc, off, 64);

    __shared__ float sdata[BLOCK / 64];
    const int lane = threadIdx.x & 63;
    const int wid  = threadIdx.x >> 6;
    if (lane == 0) sdata[wid] = acc;
    __syncthreads();
    if (threadIdx.x == 0) {
        float s = 0.0f;
        #pragma unroll
        for (int w = 0; w < BLOCK / 64; ++w) s += sdata[w];
        partial[blockIdx.x] = s;
    }
}

__global__ __launch_bounds__(256) void nll_reduce(
    const float* __restrict__ partial, float* __restrict__ out)
{
    float acc = 0.0f;
    for (int i = threadIdx.x; i < GRID; i += 256) acc += partial[i];

    #pragma unroll
    for (int off = 32; off > 0; off >>= 1) acc += __shfl_down(acc, off, 64);

    __shared__ float sdata[4];
    const int lane = threadIdx.x & 63;
    const int wid  = threadIdx.x >> 6;
    if (lane == 0) sdata[wid] = acc;
    __syncthreads();
    if (threadIdx.x == 0) {
        // loss = mean(0.5*maha + 0.5*logdet) + 0.5*D*LOG_2PI
        // acc holds 0.5*maha + sum(log diag) (logdet*0.5 == sum log)
        out[0] = (sdata[0] + sdata[1] + sdata[2] + sdata[3]) *
                     (1.0f / (float)NGROUPS) +
                 0.5f * 3.0f * LOG_2PI;
    }
}

extern "C" void kernel_launch(void* const* d_in, const int* in_sizes, int n_in,
                              void* d_out, int out_size, void* d_ws, size_t ws_size,
                              hipStream_t stream)
{
    const float* yt = (const float*)d_in[0];  // y_true        (B,S,J,D)
    const float* yp = (const float*)d_in[1];  // y_pred_mean   (B,S,J,D)
    const float* Lm = (const float*)d_in[2];  // pred_cholesky (B,S,J,D,D)
    float* out      = (float*)d_out;          // scalar mean
    float* partial  = (float*)d_ws;           // GRID floats of scratch

    nll_main<<<GRID, BLOCK, 0, stream>>>(yt, yp, Lm, partial);
    nll_reduce<<<1, 256, 0, stream>>>(partial, out);
}

// Round 3
// 45.956 us; speedup vs baseline: 1.1896x; 1.1896x over previous
//
#include <hip/hip_runtime.h>
#include <math.h>

// Problem constants (B=256, S=512, J=32, D=3)
constexpr int NGROUPS = 256 * 512 * 32;   // 4,194,304 (b,s,j) groups
constexpr int NQUAD   = NGROUPS / 4;      // 1,048,576 quads, 1 per thread
constexpr int BLOCK   = 256;
constexpr int GRID    = NQUAD / BLOCK;    // 4096 blocks, exact fit

#define LOG_2PI 1.8378770664093453f

typedef float f32x4 __attribute__((ext_vector_type(4)));

__device__ __forceinline__ float fast_rcp(float x) {
    return __builtin_amdgcn_rcpf(x);
}

__global__ __launch_bounds__(BLOCK) void nll_main(
    const float* __restrict__ yt,
    const float* __restrict__ yp,
    const float* __restrict__ Lm,
    float* __restrict__ partial)
{
    const f32x4* yt4 = reinterpret_cast<const f32x4*>(yt);
    const f32x4* yp4 = reinterpret_cast<const f32x4*>(yp);
    const f32x4* L4  = reinterpret_cast<const f32x4*>(Lm);

    const int q = blockIdx.x * BLOCK + threadIdx.x;   // one quad (4 groups)

    // Plain cached loads everywhere: the 251.7 MB working set nearly fits the
    // 256 MiB Infinity Cache, and graph replays re-read the same data -- let
    // L3 retain as much as it can. (R2's nontemporal-y experiment regressed
    // 44->55 us by forcing y to HBM on every replay.)
    float d[12];
    #pragma unroll
    for (int i = 0; i < 3; ++i) {
        f32x4 a = yt4[q * 3 + i];
        f32x4 b = yp4[q * 3 + i];
        d[i * 4 + 0] = a.x - b.x;
        d[i * 4 + 1] = a.y - b.y;
        d[i * 4 + 2] = a.z - b.z;
        d[i * 4 + 3] = a.w - b.w;
    }
    float l[36];
    #pragma unroll
    for (int i = 0; i < 9; ++i) {
        f32x4 v = L4[q * 9 + i];
        l[i * 4 + 0] = v.x;
        l[i * 4 + 1] = v.y;
        l[i * 4 + 2] = v.z;
        l[i * 4 + 3] = v.w;
    }

    float acc = 0.0f;
    #pragma unroll
    for (int g = 0; g < 4; ++g) {
        // row-major 3x3: [0]=L00 [3]=L10 [4]=L11 [6]=L20 [7]=L21 [8]=L22
        float L00 = l[g * 9 + 0];
        float L10 = l[g * 9 + 3];
        float L11 = l[g * 9 + 4];
        float L20 = l[g * 9 + 6];
        float L21 = l[g * 9 + 7];
        float L22 = l[g * 9 + 8];
        float d0 = d[g * 3 + 0];
        float d1 = d[g * 3 + 1];
        float d2 = d[g * 3 + 2];

        float r0 = fast_rcp(L00);
        float r1 = fast_rcp(L11);
        float r2 = fast_rcp(L22);
        float x0 = d0 * r0;
        float x1 = (d1 - L10 * x0) * r1;
        float x2 = (d2 - L20 * x0 - L21 * x1) * r2;
        float maha   = x0 * x0 + x1 * x1 + x2 * x2;
        float logdet = __logf(L00) + __logf(L11) + __logf(L22); // 2*sum(log)*0.5
        acc += 0.5f * maha + logdet;   // constant term added in final reduce
    }

    // wave (64-lane) shuffle reduce
    #pragma unroll
    for (int off = 32; off > 0; off >>= 1) acc += __shfl_down(acc, off, 64);

    __shared__ float sdata[BLOCK / 64];
    const int lane = threadIdx.x & 63;
    const int wid  = threadIdx.x >> 6;
    if (lane == 0) sdata[wid] = acc;
    __syncthreads();
    if (threadIdx.x == 0) {
        float s = 0.0f;
        #pragma unroll
        for (int w = 0; w < BLOCK / 64; ++w) s += sdata[w];
        partial[blockIdx.x] = s;
    }
}

__global__ __launch_bounds__(256) void nll_reduce(
    const float* __restrict__ partial, float* __restrict__ out)
{
    float acc = 0.0f;
    for (int i = threadIdx.x; i < GRID; i += 256) acc += partial[i];

    #pragma unroll
    for (int off = 32; off > 0; off >>= 1) acc += __shfl_down(acc, off, 64);

    __shared__ float sdata[4];
    const int lane = threadIdx.x & 63;
    const int wid  = threadIdx.x >> 6;
    if (lane == 0) sdata[wid] = acc;
    __syncthreads();
    if (threadIdx.x == 0) {
        // loss = mean(0.5*maha) + mean(sum log diag) + 0.5*D*LOG_2PI
        out[0] = (sdata[0] + sdata[1] + sdata[2] + sdata[3]) *
                     (1.0f / (float)NGROUPS) +
                 0.5f * 3.0f * LOG_2PI;
    }
}

extern "C" void kernel_launch(void* const* d_in, const int* in_sizes, int n_in,
                              void* d_out, int out_size, void* d_ws, size_t ws_size,
                              hipStream_t stream)
{
    const float* yt = (const float*)d_in[0];  // y_true        (B,S,J,D)
    const float* yp = (const float*)d_in[1];  // y_pred_mean   (B,S,J,D)
    const float* Lm = (const float*)d_in[2];  // pred_cholesky (B,S,J,D,D)
    float* out      = (float*)d_out;          // scalar mean
    float* partial  = (float*)d_ws;           // GRID floats of scratch

    nll_main<<<GRID, BLOCK, 0, stream>>>(yt, yp, Lm, partial);
    nll_reduce<<<1, 256, 0, stream>>>(partial, out);
}

// Round 4
// 44.078 us; speedup vs baseline: 1.2403x; 1.0426x over previous
//
#include <hip/hip_runtime.h>
#include <math.h>

// Problem constants (B=256, S=512, J=32, D=3)
constexpr int NGROUPS = 256 * 512 * 32;   // 4,194,304 (b,s,j) groups
constexpr int BLOCK   = 256;              // 1 group per thread
constexpr int GRID    = NGROUPS / BLOCK;  // 16384 blocks, exact fit

#define LOG_2PI 1.8378770664093453f

typedef float f32x4 __attribute__((ext_vector_type(4)));

__device__ __forceinline__ float fast_rcp(float x) {
    return __builtin_amdgcn_rcpf(x);
}

// Per block: 256 groups.
//   y_true slice : 256*3 floats = 192 float4 (3 KB)
//   y_pred slice : 192 float4 (3 KB)
//   L slice      : 256*9 floats = 576 float4 (9 KB)
// Total LDS = 15 KB -> 8 blocks/CU (LDS would allow 10, wave slots cap at 8)
// -> 32 waves/CU = 100% occupancy.
__global__ __launch_bounds__(BLOCK) void nll_main(
    const float* __restrict__ yt,
    const float* __restrict__ yp,
    const float* __restrict__ Lm,
    float* __restrict__ partial)
{
    __shared__ float syt[768];
    __shared__ float syp[768];
    __shared__ float sl[2304];

    const f32x4* yt4 = reinterpret_cast<const f32x4*>(yt);
    const f32x4* yp4 = reinterpret_cast<const f32x4*>(yp);
    const f32x4* L4  = reinterpret_cast<const f32x4*>(Lm);
    f32x4* syt4 = reinterpret_cast<f32x4*>(syt);
    f32x4* syp4 = reinterpret_cast<f32x4*>(syp);
    f32x4* sl4  = reinterpret_cast<f32x4*>(sl);

    const int tid = threadIdx.x;
    const int bx  = blockIdx.x;

    // Coalesced staging: lane i <-> 16 consecutive bytes. Every wave
    // instruction touches exactly 16 cache lines (vs 48 for the old
    // 48/144-B-strided per-group loads).
    if (tid < 192) {
        syt4[tid] = yt4[bx * 192 + tid];
        syp4[tid] = yp4[bx * 192 + tid];
    }
    sl4[tid]       = L4[bx * 576 + tid];
    sl4[tid + 256] = L4[bx * 576 + 256 + tid];
    if (tid < 64) sl4[tid + 512] = L4[bx * 576 + 512 + tid];
    __syncthreads();

    // Per-group operands from LDS. Read strides 3 and 9 floats: gcd(3,32)=
    // gcd(9,32)=1 -> conflict-free across a wave.
    const float d0 = syt[tid * 3 + 0] - syp[tid * 3 + 0];
    const float d1 = syt[tid * 3 + 1] - syp[tid * 3 + 1];
    const float d2 = syt[tid * 3 + 2] - syp[tid * 3 + 2];
    // row-major 3x3: [0]=L00 [3]=L10 [4]=L11 [6]=L20 [7]=L21 [8]=L22
    const float L00 = sl[tid * 9 + 0];
    const float L10 = sl[tid * 9 + 3];
    const float L11 = sl[tid * 9 + 4];
    const float L20 = sl[tid * 9 + 6];
    const float L21 = sl[tid * 9 + 7];
    const float L22 = sl[tid * 9 + 8];

    const float r0 = fast_rcp(L00);
    const float r1 = fast_rcp(L11);
    const float r2 = fast_rcp(L22);
    const float x0 = d0 * r0;
    const float x1 = (d1 - L10 * x0) * r1;
    const float x2 = (d2 - L20 * x0 - L21 * x1) * r2;
    const float maha = x0 * x0 + x1 * x1 + x2 * x2;
    // 0.5 * logdet == sum(log diag); constant term folded into final reduce.
    float acc = 0.5f * maha + __logf(L00) + __logf(L11) + __logf(L22);

    // wave (64-lane) shuffle reduce
    #pragma unroll
    for (int off = 32; off > 0; off >>= 1) acc += __shfl_down(acc, off, 64);

    __shared__ float sdata[BLOCK / 64];
    const int lane = tid & 63;
    const int wid  = tid >> 6;
    if (lane == 0) sdata[wid] = acc;
    __syncthreads();
    if (tid == 0) {
        float s = 0.0f;
        #pragma unroll
        for (int w = 0; w < BLOCK / 64; ++w) s += sdata[w];
        partial[bx] = s;
    }
}

__global__ __launch_bounds__(1024) void nll_reduce(
    const float* __restrict__ partial, float* __restrict__ out)
{
    // GRID = 16384 partials = 4096 float4
    const f32x4* p4 = reinterpret_cast<const f32x4*>(partial);
    float acc = 0.0f;
    #pragma unroll
    for (int k = 0; k < 4; ++k) {
        f32x4 v = p4[threadIdx.x + k * 1024];
        acc += v.x + v.y + v.z + v.w;
    }

    #pragma unroll
    for (int off = 32; off > 0; off >>= 1) acc += __shfl_down(acc, off, 64);

    __shared__ float sdata[16];
    const int lane = threadIdx.x & 63;
    const int wid  = threadIdx.x >> 6;
    if (lane == 0) sdata[wid] = acc;
    __syncthreads();
    if (threadIdx.x == 0) {
        float s = 0.0f;
        #pragma unroll
        for (int w = 0; w < 16; ++w) s += sdata[w];
        // loss = mean(0.5*maha + sum log diag) + 0.5*D*LOG_2PI
        out[0] = s * (1.0f / (float)NGROUPS) + 0.5f * 3.0f * LOG_2PI;
    }
}

extern "C" void kernel_launch(void* const* d_in, const int* in_sizes, int n_in,
                              void* d_out, int out_size, void* d_ws, size_t ws_size,
                              hipStream_t stream)
{
    const float* yt = (const float*)d_in[0];  // y_true        (B,S,J,D)
    const float* yp = (const float*)d_in[1];  // y_pred_mean   (B,S,J,D)
    const float* Lm = (const float*)d_in[2];  // pred_cholesky (B,S,J,D,D)
    float* out      = (float*)d_out;          // scalar mean
    float* partial  = (float*)d_ws;           // GRID floats (64 KB) of scratch

    nll_main<<<GRID, BLOCK, 0, stream>>>(yt, yp, Lm, partial);
    nll_reduce<<<1, 1024, 0, stream>>>(partial, out);
}